// Round 1
// 11021.081 us; speedup vs baseline: 1.2087x; 1.2087x over previous
//
#include <hip/hip_runtime.h>
#include <math.h>

// EncoderRNN persistent kernel, round 6.
// Changes vs round 5 (sync structure, LDS layout, numerics-critical paths all
// UNCHANGED):
//  (a) Staging thread remap: row = tid&15, k-slice = tid>>4 (was the reverse).
//      Consecutive lanes now write consecutive 2064B-strided LDS rows (stride
//      == +1 16B-slot mod 8) instead of 128B-strided same-row chunks that put
//      every consecutive-8-lane group on one 4-bank quad (8-way conflict).
//      Also makes waves 0-1 pure x-staging, waves 2-3 pure h-staging (no
//      divergent exec-mask split inside each wave).
//  (b) h-staging emits ds_write_b128 (8 hi + 8 lo uint4) instead of 32 u64.
//  (c) K split across waves: wave w owns kc in [8w,8w+8) for ALL 4 gates.
//      Each B-fragment is read once per wave and reused across 4 gates x 3
//      mfma terms -> ds_read_b128 count per CU-step drops 256 -> 64 (the 4
//      waves previously read identical data). Per-gate K-partials reduced
//      through gl2[4][4][16][20] fp32 in LDS, tree-summed in the cell.
// Predicted: SQ_LDS_BANK_CONFLICT 1.92e9 -> <4e8, dur 13.3ms -> ~10-10.8ms.

#define SEQ 1024
#define NB 32
#define NH 512
#define BH (NB*NH)
#define KP 1032   // LDS row stride in shorts = 2064 B (odd 16B slots)

typedef __attribute__((ext_vector_type(8))) short short8;
typedef __attribute__((ext_vector_type(4))) float f32x4;
typedef unsigned long long u64;

struct P {
  const int*   word;
  const float* emb;
  const float* Wih[4];   // dl = dir*2+layer: 0=fwd1,1=fwd2,2=bwd1,3=bwd2
  const float* Whh[4];
  const float* bih[4];
  const float* bhh[4];
  unsigned* flags;       // 256 slots, stride 16 u32 (one 64B line each)
  unsigned* gen;         // single 64B line
  unsigned* hpk;         // [4 dl][2 par][NB][NH] u32 = (bf16hi | bf16lo<<16)
  float* out;
};

__device__ __forceinline__ unsigned short f2bf(float x) {
  unsigned u = __float_as_uint(x);
  return (unsigned short)((u + 0x7fffu + ((u >> 16) & 1u)) >> 16);  // RNE
}
__device__ __forceinline__ float bf2f(unsigned short b) {
  return __uint_as_float(((unsigned)b) << 16);
}
__device__ __forceinline__ float sigf(float x) { return 1.0f / (1.0f + expf(-x)); }

__device__ __forceinline__ unsigned ald(const unsigned* p_) {
  return __hip_atomic_load((unsigned*)p_, __ATOMIC_RELAXED, __HIP_MEMORY_SCOPE_AGENT);
}
__device__ __forceinline__ u64 ald64(const u64* p_) {
  return __hip_atomic_load((u64*)p_, __ATOMIC_RELAXED, __HIP_MEMORY_SCOPE_AGENT);
}
__device__ __forceinline__ void ast(unsigned* p_, unsigned v) {
  __hip_atomic_store(p_, v, __ATOMIC_RELAXED, __HIP_MEMORY_SCOPE_AGENT);
}
__device__ __forceinline__ float aldf(const float* p_) {
  return __hip_atomic_load((float*)p_, __ATOMIC_RELAXED, __HIP_MEMORY_SCOPE_AGENT);
}
__device__ __forceinline__ void astf(float* p_, float v) {
  __hip_atomic_store(p_, v, __ATOMIC_RELAXED, __HIP_MEMORY_SCOPE_AGENT);
}

// stage 64 packed-u32 h elements (agent-coherent) -> 64 hi + 64 lo shorts in
// LDS, emitted as 8+8 ds_write_b128 (conflict-free under the row-major remap).
__device__ __forceinline__ void stage_h_slice(const unsigned* src,
                                              unsigned short* dHi,
                                              unsigned short* dLo) {
  u64 A[32];
#pragma unroll
  for (int q = 0; q < 32; ++q) A[q] = ald64((const u64*)src + q);
#pragma unroll
  for (int q = 0; q < 8; ++q) {
    unsigned hw[4], lw[4];
#pragma unroll
    for (int m = 0; m < 4; ++m) {
      const unsigned w0 = (unsigned)A[4*q + m];
      const unsigned w1 = (unsigned)(A[4*q + m] >> 32);
      hw[m] = (w0 & 0xffffu) | (w1 << 16);
      lw[m] = (w0 >> 16)     | (w1 & 0xffff0000u);
    }
    uint4 hv, lv;
    hv.x = hw[0]; hv.y = hw[1]; hv.z = hw[2]; hv.w = hw[3];
    lv.x = lw[0]; lv.y = lw[1]; lv.z = lw[2]; lv.w = lw[3];
    *(uint4*)(dHi + q*8) = hv;
    *(uint4*)(dLo + q*8) = lv;
  }
}

__global__ __launch_bounds__(256, 1) void enc_persist(P p) {
  extern __shared__ unsigned short smem[];
  unsigned short* xhHi = smem;              // [16][KP]
  unsigned short* xhLo = smem + 16 * KP;    // [16][KP]
  float* gl2 = (float*)(smem + 32 * KP);    // [4 wv][4 gate][16 batch][20] fp32

  const int tid  = threadIdx.x;
  const int bid  = blockIdx.x;
  const int dl   = bid >> 6;
  const int dir  = dl >> 1, layer = dl & 1;
  const int r6   = bid & 63;
  const int u0   = (r6 >> 1) * 16;   // 32 unit-groups of 16
  const int b0   = (r6 & 1) * 16;    // 2 batch-halves of 16
  const int lane = tid & 63, wv = tid >> 6;   // wave wv owns kc in [8wv, 8wv+8)

  // ---- prologue: W fragments (bf16 hi/lo) for all 4 gates, this wave's K ----
  short8 aHi[32], aLo[32];   // index gg*8+kk
  {
    const int kg = (lane >> 4) * 8;
#pragma unroll
    for (int gg = 0; gg < 4; ++gg) {
      const int gr = gg * 512 + u0 + (lane & 15);   // global gate row
      const float* Wi = p.Wih[dl] + (size_t)gr * NH;
      const float* Wh = p.Whh[dl] + (size_t)gr * NH;
#pragma unroll
      for (int kk = 0; kk < 8; ++kk) {
        const int k0 = (wv * 8 + kk) * 32 + kg;
        const float* s = (k0 < 512) ? (Wi + k0) : (Wh + (k0 - 512));
        float4 v0 = *(const float4*)s;
        float4 v1 = *(const float4*)(s + 4);
        float xs[8] = {v0.x, v0.y, v0.z, v0.w, v1.x, v1.y, v1.z, v1.w};
        short8 h8, l8;
#pragma unroll
        for (int q = 0; q < 8; ++q) {
          unsigned short hb = f2bf(xs[q]);
          h8[q] = (short)hb;
          l8[q] = (short)f2bf(xs[q] - bf2f(hb));
        }
        aHi[gg * 8 + kk] = h8; aLo[gg * 8 + kk] = l8;
      }
    }
  }

  // cell thread mapping: cb = batch-local (tid>>4), cu = unit (tid&15)
  const int cu = tid & 15, cb = tid >> 4;
  const int uG = u0 + cu;
  const float bi  = p.bih[dl][uG]        + p.bhh[dl][uG];
  const float bf_ = p.bih[dl][512 + uG]  + p.bhh[dl][512 + uG];
  const float bg  = p.bih[dl][1024 + uG] + p.bhh[dl][1024 + uG];
  const float bo  = p.bih[dl][1536 + uG] + p.bhh[dl][1536 + uG];

  float c_reg = 0.f, h_reg = 0.f;

  // staging thread mapping (REMAPPED): rb = row (tid&15), sr = k-slice (tid>>4)
  const int sr = tid >> 4;
  const int rb = tid & 15;
  const int ks = sr * 64;      // this thread's 64-short slice of the row

  int tk, tk_st;
  {
    const int to0 = dir ? (SEQ - 1) : 0;
    tk    = p.word[(size_t)to0 * NB + b0 + cb];   // cell mask token
    tk_st = p.word[(size_t)to0 * NB + b0 + rb];   // staging-row token
  }

  for (int j = 0; j <= SEQ; ++j) {
    const int act = layer ? (j >= 1) : (j < SEQ);
    const int t = layer ? (j - 1) : j;
    const int torig = dir ? (SEQ - 1 - t) : t;
    const int par = j & 1;

    if (act) {
      // ---- stage one row-slice of [x(512);h(512)] as bf16 hi/lo into LDS ----
      if (sr < 8) {   // x-part, k in [0,512)  (waves 0-1, uniform)
        if (layer == 0) {  // embedding fp32 (read-only, normal cached loads)
          const float* e = p.emb + (size_t)tk_st * NH + ks;
#pragma unroll
          for (int h2 = 0; h2 < 2; ++h2) {
            float4 v[8];
#pragma unroll
            for (int q = 0; q < 8; ++q) v[q] = *(const float4*)(e + h2 * 32 + q * 4);
#pragma unroll
            for (int q = 0; q < 4; ++q) {
              float xs[8] = {v[2*q].x, v[2*q].y, v[2*q].z, v[2*q].w,
                             v[2*q+1].x, v[2*q+1].y, v[2*q+1].z, v[2*q+1].w};
              unsigned hw[4], lw[4];
#pragma unroll
              for (int m = 0; m < 4; ++m) {
                unsigned short ha = f2bf(xs[2*m]);
                unsigned short hc = f2bf(xs[2*m+1]);
                unsigned short la = f2bf(xs[2*m]   - bf2f(ha));
                unsigned short lc = f2bf(xs[2*m+1] - bf2f(hc));
                hw[m] = (unsigned)ha | ((unsigned)hc << 16);
                lw[m] = (unsigned)la | ((unsigned)lc << 16);
              }
              uint4 hv, lv;
              hv.x=hw[0]; hv.y=hw[1]; hv.z=hw[2]; hv.w=hw[3];
              lv.x=lw[0]; lv.y=lw[1]; lv.z=lw[2]; lv.w=lw[3];
              *(uint4*)(xhHi + rb * KP + ks + h2 * 32 + q * 8) = hv;
              *(uint4*)(xhLo + rb * KP + ks + h2 * 32 + q * 8) = lv;
            }
          }
        } else {      // layer2 x = layer1 h (packed u32, agent-coherent)
          const size_t hb = (size_t)((dl - 1) * 2 + par) * BH + (size_t)(b0 + rb) * NH + ks;
          stage_h_slice(p.hpk + hb, xhHi + rb * KP + ks, xhLo + rb * KP + ks);
        }
      } else {        // recurrent half, k in [512,1024)  (waves 2-3, uniform)
        const size_t hb = (size_t)(dl * 2 + par) * BH + (size_t)(b0 + rb) * NH + (ks - 512);
        stage_h_slice(p.hpk + hb, xhHi + rb * KP + ks, xhLo + rb * KP + ks);
      }
    }

    // prefetch next step's tokens (latency hides under MFMA+cell+barrier)
    int tk_nx = tk, tk_st_nx = tk_st;
    if (j < SEQ) {
      int t_nx = layer ? j : (j + 1);
      if (t_nx > SEQ - 1) t_nx = SEQ - 1;
      const int to_nx = dir ? (SEQ - 1 - t_nx) : t_nx;
      tk_nx    = p.word[(size_t)to_nx * NB + b0 + cb];
      tk_st_nx = p.word[(size_t)to_nx * NB + b0 + rb];
    }

    __syncthreads();

    if (act) {
      // ---- K-split MFMA: this wave sums kc in [8wv,8wv+8) for all 4 gates.
      // Each B-fragment read once, reused 4 gates x {hi*hi, lo*hi, hi*lo}.
      f32x4 aA[4], aBC[4];
#pragma unroll
      for (int gg = 0; gg < 4; ++gg) {
        aA[gg]  = (f32x4){0.f, 0.f, 0.f, 0.f};
        aBC[gg] = (f32x4){0.f, 0.f, 0.f, 0.f};
      }
      const unsigned short* bp = xhHi + (lane & 15) * KP + (lane >> 4) * 8;
      const unsigned short* bq = xhLo + (lane & 15) * KP + (lane >> 4) * 8;
#pragma unroll
      for (int kk = 0; kk < 8; ++kk) {
        const int kc = wv * 8 + kk;
        short8 bH = *(const short8*)(bp + kc * 32);
        short8 bL = *(const short8*)(bq + kc * 32);
#pragma unroll
        for (int gg = 0; gg < 4; ++gg) {
          aA[gg]  = __builtin_amdgcn_mfma_f32_16x16x32_bf16(aHi[gg*8+kk], bH, aA[gg],  0, 0, 0);
          aBC[gg] = __builtin_amdgcn_mfma_f32_16x16x32_bf16(aLo[gg*8+kk], bH, aBC[gg], 0, 0, 0);
          aBC[gg] = __builtin_amdgcn_mfma_f32_16x16x32_bf16(aHi[gg*8+kk], bL, aBC[gg], 0, 0, 0);
        }
      }
      // C/D (m89): col = lane&15 = batch, row = (lane>>4)*4 + reg = unit
#pragma unroll
      for (int gg = 0; gg < 4; ++gg) {
        f32x4 acc = aA[gg] + aBC[gg];
        *(f32x4*)&gl2[((wv * 4 + gg) * 16 + (lane & 15)) * 20 + (lane >> 4) * 4] = acc;
      }
    }
    __syncthreads();

    if (act) {
      // ---- fused cell: tree-sum the 4 waves' K-partials ----
#define GL2(w_,g_) gl2[(((w_) * 4 + (g_)) * 16 + cb) * 20 + cu]
      const float vi = ((GL2(0,0)+GL2(1,0)) + (GL2(2,0)+GL2(3,0))) + bi;
      const float vf = ((GL2(0,1)+GL2(1,1)) + (GL2(2,1)+GL2(3,1))) + bf_;
      const float vg = ((GL2(0,2)+GL2(1,2)) + (GL2(2,2)+GL2(3,2))) + bg;
      const float vo = ((GL2(0,3)+GL2(1,3)) + (GL2(2,3)+GL2(3,3))) + bo;
#undef GL2
      float cn = sigf(vf) * c_reg + sigf(vi) * tanhf(vg);
      float hn = sigf(vo) * tanhf(cn);
      if (tk == 1) { cn = c_reg; hn = h_reg; }
      c_reg = cn; h_reg = hn;
      const unsigned short hh = f2bf(hn);
      const unsigned short hl = f2bf(hn - bf2f(hh));
      const size_t hix = (size_t)(dl * 2 + (par ^ 1)) * BH + (size_t)(b0 + cb) * NH + uG;
      ast(p.hpk + hix, (unsigned)hh | ((unsigned)hl << 16));
      if (layer == 1) {
        // store-then-add ordering guaranteed by the device barrier per step
        const size_t oi = (size_t)torig * BH + (size_t)(b0 + cb) * NH + uG;
        if (dir == 0) {
          if (torig <= 511) astf(p.out + oi, hn);
          else              astf(p.out + oi, aldf(p.out + oi) + hn);
        } else {
          const float v = 0.5f * hn;
          if (torig >= 512) astf(p.out + oi, v);
          else              astf(p.out + oi, aldf(p.out + oi) + v);
        }
      }
    }

    tk = tk_nx; tk_st = tk_st_nx;

    // ---- flat leader device barrier (relaxed atomics only, no fences) ----
    __syncthreads();   // drains vmcnt -> all sc1 stores acked at coherence point
    if (tid == 0)
      ast(p.flags + (size_t)bid * 16, (unsigned)(j + 1));
    if (bid == 0) {
      unsigned* f = p.flags + (size_t)tid * 16;
      while (ald(f) < (unsigned)(j + 1)) __builtin_amdgcn_s_sleep(1);
      __syncthreads();
      if (tid == 0) ast(p.gen, (unsigned)(j + 1));
    } else {
      if (tid < 64) {
        while (ald(p.gen) < (unsigned)(j + 1)) __builtin_amdgcn_s_sleep(1);
      }
      __syncthreads();
    }
  }

  // ---- epilogue: backward final carries bh1,bc1,bh2,bc2 ----
  if (dl == 2) {
    p.out[(size_t)SEQ * BH + 0 * (size_t)BH + (size_t)(b0 + cb) * NH + uG] = h_reg;
    p.out[(size_t)SEQ * BH + 1 * (size_t)BH + (size_t)(b0 + cb) * NH + uG] = c_reg;
  } else if (dl == 3) {
    p.out[(size_t)SEQ * BH + 2 * (size_t)BH + (size_t)(b0 + cb) * NH + uG] = h_reg;
    p.out[(size_t)SEQ * BH + 3 * (size_t)BH + (size_t)(b0 + cb) * NH + uG] = c_reg;
  }
}

extern "C" void kernel_launch(void* const* d_in, const int* in_sizes, int n_in,
                              void* d_out, int out_size, void* d_ws, size_t ws_size,
                              hipStream_t stream) {
  P p;
  p.word = (const int*)d_in[0];
  p.emb  = (const float*)d_in[1];
  for (int i = 0; i < 4; ++i) {
    p.Wih[i] = (const float*)d_in[2 + i * 4 + 0];
    p.Whh[i] = (const float*)d_in[2 + i * 4 + 1];
    p.bih[i] = (const float*)d_in[2 + i * 4 + 2];
    p.bhh[i] = (const float*)d_in[2 + i * 4 + 3];
  }
  unsigned char* ws = (unsigned char*)d_ws;
  p.flags = (unsigned*)ws;                       // 16 KB (256 x 64B slots)
  p.gen   = (unsigned*)(ws + 16384);             // one 64B line
  p.hpk   = (unsigned*)(ws + 16448);             // 512 KB packed h
  p.out   = (float*)d_out;

  hipMemsetAsync(d_ws, 0, 16448 + (size_t)8 * BH * 4, stream);

  // used: 32*KP*2 + 4*4*16*20*4 = 66048 + 20480 = 86528 B; request 88 KB
  // to keep 1 block/CU
  const int smem = 90112;
  hipFuncSetAttribute(reinterpret_cast<const void*>(enc_persist),
                      hipFuncAttributeMaxDynamicSharedMemorySize, smem);
  hipLaunchKernelGGL(enc_persist, dim3(256), dim3(256), smem, stream, p);
}